// Round 1
// baseline (8274.007 us; speedup 1.0000x reference)
//
#include <hip/hip_runtime.h>

// ---------------------------------------------------------------------------
// GRU (T=256, B=16, HID=1024, EMB=512, VOCAB=32000) + vocab projection.
// Structure:
//   prep_*   : cast weights/embeddings to bf16, split W into h-part / x-part
//   gemm_bt  : C[M,N] = A[M,K] * B[N,K]^T, bf16 MFMA 16x16x32, 128x128 tile
//              (used for Gx precompute and the final 268-GFLOP projection)
//   gru_persistent: 64 blocks, weights LDS-resident, 2 spin grid-barriers/step
// ---------------------------------------------------------------------------

using bf16x8 = __attribute__((ext_vector_type(8))) __bf16;
using f32x4  = __attribute__((ext_vector_type(4))) float;

__device__ __forceinline__ unsigned short f2bf(float f) {
  unsigned u = __builtin_bit_cast(unsigned, f);
  u += 0x7FFFu + ((u >> 16) & 1u);          // RNE
  return (unsigned short)(u >> 16);
}

__device__ __forceinline__ f32x4 mfma16(bf16x8 a, bf16x8 b, f32x4 c) {
  return __builtin_amdgcn_mfma_f32_16x16x32_bf16(a, b, c, 0, 0, 0);
}

// ---------------- prep kernels ----------------

// Split Wz/Wr/W [1024][1536] fp32 into Whall [3][1024][1024] bf16 (h-part)
// and Wxall [3][1024][512] bf16 (x-part). 3*1024*1536/4 = 1,179,648 float4s.
__global__ void prep_w(const float* __restrict__ Wz, const float* __restrict__ Wr,
                       const float* __restrict__ Wm,
                       unsigned short* __restrict__ Whall,
                       unsigned short* __restrict__ Wxall) {
  int i = blockIdx.x * 256 + threadIdx.x;
  int g   = i / 393216;            // 1024*1536/4
  int rem = i % 393216;
  int j   = rem / 384;             // 1536/4
  int k   = (rem % 384) * 4;
  const float* src = (g == 0) ? Wz : (g == 1) ? Wr : Wm;
  float4 v = *(const float4*)(src + (size_t)j * 1536 + k);
  ushort4 o;
  o.x = f2bf(v.x); o.y = f2bf(v.y); o.z = f2bf(v.z); o.w = f2bf(v.w);
  if (k < 1024)
    *(ushort4*)(Whall + ((size_t)(g * 1024 + j) * 1024 + k)) = o;
  else
    *(ushort4*)(Wxall + ((size_t)(g * 1024 + j) * 512 + (k - 1024))) = o;
}

// Wd [32000][1024] fp32 -> bf16. 8,192,000 float4s.
__global__ void prep_wd(const float* __restrict__ Wd, unsigned short* __restrict__ Wdbf) {
  size_t i = (size_t)blockIdx.x * 256 + threadIdx.x;
  float4 v = *(const float4*)(Wd + i * 4);
  ushort4 o;
  o.x = f2bf(v.x); o.y = f2bf(v.y); o.z = f2bf(v.z); o.w = f2bf(v.w);
  *(ushort4*)(Wdbf + i * 4) = o;
}

// xe_bf[tb][512] = bf16(emb[x[tb]]). 4096*128 = 524,288 float4s.
__global__ void prep_xe(const int* __restrict__ x, const float* __restrict__ emb,
                        unsigned short* __restrict__ xebf) {
  int i  = blockIdx.x * 256 + threadIdx.x;
  int tb = i >> 7, k = (i & 127) * 4;
  int tok = x[tb];
  float4 v = *(const float4*)(emb + (size_t)tok * 512 + k);
  ushort4 o;
  o.x = f2bf(v.x); o.y = f2bf(v.y); o.z = f2bf(v.z); o.w = f2bf(v.w);
  *(ushort4*)(xebf + (size_t)tb * 512 + k) = o;
}

// h32/hbf init from input h. 16384 elements.
__global__ void prep_h(const float* __restrict__ h, float* __restrict__ h32,
                       unsigned short* __restrict__ hbf) {
  int i = blockIdx.x * 256 + threadIdx.x;
  float v = h[i];
  h32[i] = v;
  hbf[i] = f2bf(v);
}

// ---------------- GEMM: C[M,N] = A[M,K] x B[N,K]^T (bf16 in, fp32 out) ------
// 128x128 tile, BK=32, 4 waves (2x2), 4x4 16x16 acc tiles per wave.
// LDS rows padded to 5 uint4 (80 B) -> conflict-free-ish ds_read_b128.
// grid = (M/128, N/128); consecutive blockIdx.x share the B-tile (L2 reuse).
__global__ __launch_bounds__(256) void gemm_bt(
    const unsigned short* __restrict__ A, const unsigned short* __restrict__ B,
    float* __restrict__ C, int M, int N, int K, int lda, int ldb, int ldc) {
  __shared__ uint4 As[128 * 5];
  __shared__ uint4 Bs[128 * 5];
  const int tid  = threadIdx.x;
  const int wid  = tid >> 6, lane = tid & 63;
  const int wr   = wid >> 1, wc = wid & 1;
  const int m0   = blockIdx.x * 128, n0 = blockIdx.y * 128;
  const int lr   = lane & 15, lk = lane >> 4;

  f32x4 acc[4][4] = {};
  const int nk = K >> 5;
  for (int kt = 0; kt < nk; ++kt) {
#pragma unroll
    for (int c = 0; c < 2; ++c) {
      int chunk = c * 256 + tid;
      int row = chunk >> 2, kc = chunk & 3;
      uint4 va = *(const uint4*)(A + (size_t)(m0 + row) * lda + kt * 32 + kc * 8);
      uint4 vb = *(const uint4*)(B + (size_t)(n0 + row) * ldb + kt * 32 + kc * 8);
      As[row * 5 + kc] = va;
      Bs[row * 5 + kc] = vb;
    }
    __syncthreads();
    bf16x8 af[4], bg[4];
#pragma unroll
    for (int i = 0; i < 4; ++i) {
      af[i] = __builtin_bit_cast(bf16x8, As[(wr * 64 + i * 16 + lr) * 5 + lk]);
      bg[i] = __builtin_bit_cast(bf16x8, Bs[(wc * 64 + i * 16 + lr) * 5 + lk]);
    }
#pragma unroll
    for (int i = 0; i < 4; ++i)
#pragma unroll
      for (int j = 0; j < 4; ++j)
        acc[i][j] = mfma16(af[i], bg[j], acc[i][j]);
    __syncthreads();
  }
  // C/D layout: col = lane&15, row = (lane>>4)*4 + q
#pragma unroll
  for (int i = 0; i < 4; ++i) {
    int mb = m0 + wr * 64 + i * 16 + lk * 4;
#pragma unroll
    for (int j = 0; j < 4; ++j) {
      int n = n0 + wc * 64 + j * 16 + lr;
#pragma unroll
      for (int q = 0; q < 4; ++q)
        C[(size_t)(mb + q) * ldc + n] = acc[i][j][q];
    }
  }
}

// ---------------- persistent GRU kernel ----------------

#define NBLK 64

__device__ __forceinline__ void grid_bar(unsigned* cnt, unsigned* gen) {
  __threadfence();            // release our writes agent-wide
  __syncthreads();
  if (threadIdx.x == 0) {
    unsigned g = __hip_atomic_load(gen, __ATOMIC_ACQUIRE, __HIP_MEMORY_SCOPE_AGENT);
    unsigned old = __hip_atomic_fetch_add(cnt, 1u, __ATOMIC_ACQ_REL, __HIP_MEMORY_SCOPE_AGENT);
    if (old == NBLK - 1u) {
      __hip_atomic_store(cnt, 0u, __ATOMIC_RELAXED, __HIP_MEMORY_SCOPE_AGENT);
      __hip_atomic_fetch_add(gen, 1u, __ATOMIC_RELEASE, __HIP_MEMORY_SCOPE_AGENT);
    } else {
      while (__hip_atomic_load(gen, __ATOMIC_ACQUIRE, __HIP_MEMORY_SCOPE_AGENT) == g)
        __builtin_amdgcn_s_sleep(2);
    }
  }
  __syncthreads();
  __threadfence();            // acquire: invalidate so we see others' writes
}

// 64 blocks x 256 threads; block owns 16 output columns across all gates.
// LDS: weights 96 KB (XOR-swizzled for conflict-free ds_read_b128) + 8 KB red.
// 1 block/CU -> all 64 co-resident (spin barrier safe).
__global__ __launch_bounds__(256, 1) void gru_persistent(
    const unsigned short* __restrict__ Whall, const float* __restrict__ Gx,
    float* __restrict__ h32, unsigned short* __restrict__ hbf,
    unsigned short* __restrict__ rh, float* __restrict__ outh,
    unsigned short* __restrict__ allhbf, unsigned* __restrict__ bar) {
  __shared__ uint4 Wl[3 * 16 * 128];            // [gate][col][k/8], swizzled
  __shared__ float red[2][4][16][16];           // [gate-slot][wave][b][col]

  const int tid  = threadIdx.x;
  const int lane = tid & 63, wq = tid >> 6;
  const int c0   = blockIdx.x * 16;
  const int lr   = lane & 15, lk = lane >> 4;
  const int bKu  = wq * 32;                     // wave's K-quarter in uint4 units

  // stage this block's weight slices (3 gates x 16 cols x 1024 K, bf16)
  for (int it = 0; it < 24; ++it) {
    int chunk = it * 256 + tid;                 // 0..6143
    int g = chunk >> 11, rem = chunk & 2047;
    int cl = rem >> 7, k8 = rem & 127;
    uint4 v = *(const uint4*)(Whall + ((size_t)(g * 1024 + c0 + cl) * 1024 + k8 * 8));
    Wl[(g * 16 + cl) * 128 + (k8 ^ (cl & 7))] = v;
  }
  __syncthreads();

  const uint4* hb4 = (const uint4*)hbf;
  const uint4* rh4 = (const uint4*)rh;
  unsigned* cnt = bar;
  unsigned* gen = bar + 1;

  const int b_  = tid >> 4, cl_ = tid & 15;
  const int cg  = c0 + cl_;
  float zv = 0.f, hp = 0.f;

  for (int t = 0; t < 256; ++t) {
    // ---- phase 1: z, r ----
    f32x4 az = {}, ar = {};
#pragma unroll
    for (int kk = 0; kk < 8; ++kk) {
      int ku = bKu + kk * 4 + lk;               // 0..127
      bf16x8 a  = __builtin_bit_cast(bf16x8, hb4[lr * 128 + ku]);
      bf16x8 bz = __builtin_bit_cast(bf16x8, Wl[(0 * 16 + lr) * 128 + (ku ^ (lr & 7))]);
      bf16x8 br = __builtin_bit_cast(bf16x8, Wl[(1 * 16 + lr) * 128 + (ku ^ (lr & 7))]);
      az = mfma16(a, bz, az);
      ar = mfma16(a, br, ar);
    }
#pragma unroll
    for (int q = 0; q < 4; ++q) {
      red[0][wq][lk * 4 + q][lr] = az[q];
      red[1][wq][lk * 4 + q][lr] = ar[q];
    }
    __syncthreads();
    {
      int tb = t * 16 + b_;
      float sz = red[0][0][b_][cl_] + red[0][1][b_][cl_] + red[0][2][b_][cl_] +
                 red[0][3][b_][cl_] + Gx[(size_t)tb * 3072 + cg];
      float sr = red[1][0][b_][cl_] + red[1][1][b_][cl_] + red[1][2][b_][cl_] +
                 red[1][3][b_][cl_] + Gx[(size_t)tb * 3072 + 1024 + cg];
      zv = 1.f / (1.f + __expf(-sz));
      float rv = 1.f / (1.f + __expf(-sr));
      hp = h32[b_ * 1024 + cg];
      rh[b_ * 1024 + cg] = f2bf(rv * hp);
    }
    grid_bar(cnt, gen);

    // ---- phase 2: cand, h_new ----
    f32x4 ac = {};
#pragma unroll
    for (int kk = 0; kk < 8; ++kk) {
      int ku = bKu + kk * 4 + lk;
      bf16x8 a  = __builtin_bit_cast(bf16x8, rh4[lr * 128 + ku]);
      bf16x8 bc = __builtin_bit_cast(bf16x8, Wl[(2 * 16 + lr) * 128 + (ku ^ (lr & 7))]);
      ac = mfma16(a, bc, ac);
    }
#pragma unroll
    for (int q = 0; q < 4; ++q) red[0][wq][lk * 4 + q][lr] = ac[q];
    __syncthreads();
    {
      int tb = t * 16 + b_;
      float sc = red[0][0][b_][cl_] + red[0][1][b_][cl_] + red[0][2][b_][cl_] +
                 red[0][3][b_][cl_] + Gx[(size_t)tb * 3072 + 2048 + cg];
      float cand = tanhf(sc);
      float hn = (1.f - zv) * hp + zv * cand;
      h32[b_ * 1024 + cg] = hn;
      hbf[b_ * 1024 + cg] = f2bf(hn);
      outh[(size_t)tb * 1024 + cg] = hn;
      allhbf[(size_t)tb * 1024 + cg] = f2bf(hn);
    }
    grid_bar(cnt, gen);
  }
}

// ---------------- workspace layout (bytes) ----------------
constexpr size_t OFF_WH  = 0;                                  // 6,291,456
constexpr size_t OFF_WX  = OFF_WH + 3ull * 1024 * 1024 * 2;    // +3 MB
constexpr size_t OFF_WD  = OFF_WX + 3ull * 1024 * 512 * 2;     // +65.5 MB
constexpr size_t OFF_XE  = OFF_WD + 32000ull * 1024 * 2;       // +4 MB
constexpr size_t OFF_GX  = OFF_XE + 4096ull * 512 * 2;         // +50.3 MB
constexpr size_t OFF_AH  = OFF_GX + 4096ull * 3072 * 4;        // +8.4 MB
constexpr size_t OFF_H32 = OFF_AH + 4096ull * 1024 * 2;
constexpr size_t OFF_HBF = OFF_H32 + 16384ull * 4;
constexpr size_t OFF_RH  = OFF_HBF + 16384ull * 2;
constexpr size_t OFF_BAR = OFF_RH + 16384ull * 2;              // 16 bytes

extern "C" void kernel_launch(void* const* d_in, const int* in_sizes, int n_in,
                              void* d_out, int out_size, void* d_ws, size_t ws_size,
                              hipStream_t stream) {
  const int*   x   = (const int*)d_in[0];
  const float* h0  = (const float*)d_in[1];
  const float* emb = (const float*)d_in[2];
  const float* Wz  = (const float*)d_in[3];
  const float* Wr  = (const float*)d_in[4];
  const float* Wm  = (const float*)d_in[5];
  const float* Wd  = (const float*)d_in[6];

  float* out_h = (float*)d_out;                        // [256*16, 1024]
  float* out_y = out_h + 4096ull * 1024;               // [256*16, 32000]

  char* ws = (char*)d_ws;
  unsigned short* Whall = (unsigned short*)(ws + OFF_WH);
  unsigned short* Wxall = (unsigned short*)(ws + OFF_WX);
  unsigned short* Wdbf  = (unsigned short*)(ws + OFF_WD);
  unsigned short* xebf  = (unsigned short*)(ws + OFF_XE);
  float*          Gx    = (float*)(ws + OFF_GX);
  unsigned short* allh  = (unsigned short*)(ws + OFF_AH);
  float*          h32   = (float*)(ws + OFF_H32);
  unsigned short* hbf   = (unsigned short*)(ws + OFF_HBF);
  unsigned short* rh    = (unsigned short*)(ws + OFF_RH);
  unsigned*       bar   = (unsigned*)(ws + OFF_BAR);

  hipMemsetAsync(bar, 0, 16, stream);

  prep_w <<<4608, 256, 0, stream>>>(Wz, Wr, Wm, Whall, Wxall);
  prep_wd<<<32000, 256, 0, stream>>>(Wd, Wdbf);
  prep_xe<<<2048, 256, 0, stream>>>(x, emb, xebf);
  prep_h <<<64, 256, 0, stream>>>(h0, h32, hbf);

  // Gx[tb][g*1024+c] = xe[tb] . Wx_g[c]   (M=4096, N=3072, K=512)
  gemm_bt<<<dim3(32, 24), 256, 0, stream>>>(xebf, Wxall, Gx,
                                            4096, 3072, 512, 512, 512, 3072);

  gru_persistent<<<NBLK, 256, 0, stream>>>(Whall, Gx, h32, hbf, rh,
                                           out_h, allh, bar);

  // all_y = all_h . Wd^T   (M=4096, N=32000, K=1024)
  gemm_bt<<<dim3(32, 250), 256, 0, stream>>>(allh, Wdbf, out_y,
                                             4096, 32000, 1024, 1024, 1024, 32000);
}

// Round 2
// 2273.935 us; speedup vs baseline: 3.6386x; 3.6386x over previous
//
#include <hip/hip_runtime.h>

// ---------------------------------------------------------------------------
// GRU (T=256, B=16, HID=1024, EMB=512, VOCAB=32000) + vocab projection.
//   prep_*   : cast weights/embeddings to bf16, split W into h-part / x-part
//   gemm_bt  : C[M,N] = A[M,K] * B[N,K]^T, bf16 MFMA 16x16x32, 128x128 tile
//   gru_persistent: 64 blocks, weights LDS-resident.
//     Cross-block exchange (hbf, rh) via device-scope RELAXED atomics
//     (sc0 sc1 uncached -> coherence point; NO L2 wbl2/inv anywhere).
//     Grid barrier = per-block flag array, relaxed store + 64-lane poll.
// ---------------------------------------------------------------------------

using bf16x8 = __attribute__((ext_vector_type(8))) __bf16;
using f32x4  = __attribute__((ext_vector_type(4))) float;
using u64x2  = __attribute__((ext_vector_type(2))) unsigned long long;

__device__ __forceinline__ unsigned short f2bf(float f) {
  unsigned u = __builtin_bit_cast(unsigned, f);
  u += 0x7FFFu + ((u >> 16) & 1u);          // RNE
  return (unsigned short)(u >> 16);
}

__device__ __forceinline__ f32x4 mfma16(bf16x8 a, bf16x8 b, f32x4 c) {
  return __builtin_amdgcn_mfma_f32_16x16x32_bf16(a, b, c, 0, 0, 0);
}

__device__ __forceinline__ unsigned long long uld64(const unsigned long long* p) {
  return __hip_atomic_load(p, __ATOMIC_RELAXED, __HIP_MEMORY_SCOPE_AGENT);
}
__device__ __forceinline__ void ust32(unsigned* p, unsigned v) {
  __hip_atomic_store(p, v, __ATOMIC_RELAXED, __HIP_MEMORY_SCOPE_AGENT);
}

// ---------------- prep kernels ----------------

__global__ void prep_w(const float* __restrict__ Wz, const float* __restrict__ Wr,
                       const float* __restrict__ Wm,
                       unsigned short* __restrict__ Whall,
                       unsigned short* __restrict__ Wxall) {
  int i = blockIdx.x * 256 + threadIdx.x;
  int g   = i / 393216;            // 1024*1536/4
  int rem = i % 393216;
  int j   = rem / 384;             // 1536/4
  int k   = (rem % 384) * 4;
  const float* src = (g == 0) ? Wz : (g == 1) ? Wr : Wm;
  float4 v = *(const float4*)(src + (size_t)j * 1536 + k);
  ushort4 o;
  o.x = f2bf(v.x); o.y = f2bf(v.y); o.z = f2bf(v.z); o.w = f2bf(v.w);
  if (k < 1024)
    *(ushort4*)(Whall + ((size_t)(g * 1024 + j) * 1024 + k)) = o;
  else
    *(ushort4*)(Wxall + ((size_t)(g * 1024 + j) * 512 + (k - 1024))) = o;
}

__global__ void prep_wd(const float* __restrict__ Wd, unsigned short* __restrict__ Wdbf) {
  size_t i = (size_t)blockIdx.x * 256 + threadIdx.x;
  float4 v = *(const float4*)(Wd + i * 4);
  ushort4 o;
  o.x = f2bf(v.x); o.y = f2bf(v.y); o.z = f2bf(v.z); o.w = f2bf(v.w);
  *(ushort4*)(Wdbf + i * 4) = o;
}

__global__ void prep_xe(const int* __restrict__ x, const float* __restrict__ emb,
                        unsigned short* __restrict__ xebf) {
  int i  = blockIdx.x * 256 + threadIdx.x;
  int tb = i >> 7, k = (i & 127) * 4;
  int tok = x[tb];
  float4 v = *(const float4*)(emb + (size_t)tok * 512 + k);
  ushort4 o;
  o.x = f2bf(v.x); o.y = f2bf(v.y); o.z = f2bf(v.z); o.w = f2bf(v.w);
  *(ushort4*)(xebf + (size_t)tb * 512 + k) = o;
}

__global__ void prep_h(const float* __restrict__ h, unsigned short* __restrict__ hbf) {
  int i = blockIdx.x * 256 + threadIdx.x;
  hbf[i] = f2bf(h[i]);
}

// ---------------- GEMM: C[M,N] = A[M,K] x B[N,K]^T (bf16 in, fp32 out) ------
__global__ __launch_bounds__(256) void gemm_bt(
    const unsigned short* __restrict__ A, const unsigned short* __restrict__ B,
    float* __restrict__ C, int M, int N, int K, int lda, int ldb, int ldc) {
  __shared__ uint4 As[128 * 5];
  __shared__ uint4 Bs[128 * 5];
  const int tid  = threadIdx.x;
  const int wid  = tid >> 6, lane = tid & 63;
  const int wr   = wid >> 1, wc = wid & 1;
  const int m0   = blockIdx.x * 128, n0 = blockIdx.y * 128;
  const int lr   = lane & 15, lk = lane >> 4;

  f32x4 acc[4][4] = {};
  const int nk = K >> 5;
  for (int kt = 0; kt < nk; ++kt) {
#pragma unroll
    for (int c = 0; c < 2; ++c) {
      int chunk = c * 256 + tid;
      int row = chunk >> 2, kc = chunk & 3;
      uint4 va = *(const uint4*)(A + (size_t)(m0 + row) * lda + kt * 32 + kc * 8);
      uint4 vb = *(const uint4*)(B + (size_t)(n0 + row) * ldb + kt * 32 + kc * 8);
      As[row * 5 + kc] = va;
      Bs[row * 5 + kc] = vb;
    }
    __syncthreads();
    bf16x8 af[4], bg[4];
#pragma unroll
    for (int i = 0; i < 4; ++i) {
      af[i] = __builtin_bit_cast(bf16x8, As[(wr * 64 + i * 16 + lr) * 5 + lk]);
      bg[i] = __builtin_bit_cast(bf16x8, Bs[(wc * 64 + i * 16 + lr) * 5 + lk]);
    }
#pragma unroll
    for (int i = 0; i < 4; ++i)
#pragma unroll
      for (int j = 0; j < 4; ++j)
        acc[i][j] = mfma16(af[i], bg[j], acc[i][j]);
    __syncthreads();
  }
#pragma unroll
  for (int i = 0; i < 4; ++i) {
    int mb = m0 + wr * 64 + i * 16 + lk * 4;
#pragma unroll
    for (int j = 0; j < 4; ++j) {
      int n = n0 + wc * 64 + j * 16 + lr;
#pragma unroll
      for (int q = 0; q < 4; ++q)
        C[(size_t)(mb + q) * ldc + n] = acc[i][j][q];
    }
  }
}

// ---------------- persistent GRU kernel ----------------

#define NBLK 64

// Per-block flag barrier. flags[bid*32], 128B stride (no line sharing).
// Relaxed everywhere: exchanged data uses sc0/sc1 uncached atomics, and the
// __syncthreads() here drains vmcnt(0) (compiler-guaranteed before s_barrier),
// so data is at the coherence point before the flag is raised. No L2 flush.
__device__ __forceinline__ void flag_bar(unsigned* flags, unsigned seq) {
  __syncthreads();
  if (threadIdx.x < 64) {
    if (threadIdx.x == 0)
      ust32(&flags[blockIdx.x * 32], seq);
    unsigned* f = &flags[threadIdx.x * 32];
    while (__hip_atomic_load(f, __ATOMIC_RELAXED, __HIP_MEMORY_SCOPE_AGENT) < seq) {}
  }
  __syncthreads();
}

// 64 blocks x 256 threads; block owns 16 output columns of all 3 gates.
// Weights 96 KB LDS (XOR-swizzled); h kept fp32 in registers (thread owns
// one (b,c) element); hbf/rh exchanged via uncached device-scope atomics.
__global__ __launch_bounds__(256, 1) void gru_persistent(
    const unsigned short* __restrict__ Whall, const float* __restrict__ Gx,
    const float* __restrict__ h0,
    unsigned short* __restrict__ hbf, unsigned short* __restrict__ rh,
    float* __restrict__ outh, unsigned short* __restrict__ allhbf,
    unsigned* __restrict__ flags) {
  __shared__ uint4 Wl[3 * 16 * 128];            // [gate][col][k/8], swizzled
  __shared__ float red[2][4][16][16];           // [slot][wave][b][col]

  const int tid  = threadIdx.x;
  const int lane = tid & 63, wq = tid >> 6;
  const int c0   = blockIdx.x * 16;
  const int lr   = lane & 15, lk = lane >> 4;
  const int bKu  = wq * 32;

  for (int it = 0; it < 24; ++it) {
    int chunk = it * 256 + tid;                 // 0..6143
    int g = chunk >> 11, rem = chunk & 2047;
    int cl = rem >> 7, k8 = rem & 127;
    uint4 v = *(const uint4*)(Whall + ((size_t)(g * 1024 + c0 + cl) * 1024 + k8 * 8));
    Wl[(g * 16 + cl) * 128 + (k8 ^ (cl & 7))] = v;
  }

  const unsigned long long* hb8 = (const unsigned long long*)hbf;
  const unsigned long long* rh8 = (const unsigned long long*)rh;

  const int b_  = tid >> 4, cl_ = tid & 15;
  const int cg  = c0 + cl_;
  float hp = h0[b_ * 1024 + cg];                // h lives in registers
  float zv = 0.f;
  __syncthreads();

  for (int t = 0; t < 256; ++t) {
    const size_t tb = (size_t)t * 16 + b_;
    // prefetch Gx (hidden under MFMAs)
    float gz = Gx[tb * 3072 + cg];
    float gr = Gx[tb * 3072 + 1024 + cg];
    float gc = Gx[tb * 3072 + 2048 + cg];

    // ---- phase 1: z, r ----
    f32x4 az = {}, ar = {};
#pragma unroll
    for (int kk = 0; kk < 8; ++kk) {
      int ku = bKu + kk * 4 + lk;               // 0..127
      int e  = (lr * 128 + ku) * 2;
      u64x2 u;
      u.x = uld64(hb8 + e);
      u.y = uld64(hb8 + e + 1);
      bf16x8 a  = __builtin_bit_cast(bf16x8, u);
      bf16x8 bz = __builtin_bit_cast(bf16x8, Wl[(0 * 16 + lr) * 128 + (ku ^ (lr & 7))]);
      bf16x8 br = __builtin_bit_cast(bf16x8, Wl[(1 * 16 + lr) * 128 + (ku ^ (lr & 7))]);
      az = mfma16(a, bz, az);
      ar = mfma16(a, br, ar);
    }
#pragma unroll
    for (int q = 0; q < 4; ++q) {
      red[0][wq][lk * 4 + q][lr] = az[q];
      red[1][wq][lk * 4 + q][lr] = ar[q];
    }
    __syncthreads();
    {
      float sz = red[0][0][b_][cl_] + red[0][1][b_][cl_] + red[0][2][b_][cl_] +
                 red[0][3][b_][cl_] + gz;
      float sr = red[1][0][b_][cl_] + red[1][1][b_][cl_] + red[1][2][b_][cl_] +
                 red[1][3][b_][cl_] + gr;
      zv = 1.f / (1.f + __expf(-sz));
      float rv = 1.f / (1.f + __expf(-sr));
      unsigned short my = f2bf(rv * hp);
      unsigned other = __shfl_xor((unsigned)my, 1);
      if ((cl_ & 1) == 0)
        ust32((unsigned*)rh + ((b_ * 1024 + cg) >> 1), (unsigned)my | (other << 16));
    }
    flag_bar(flags, 2 * t + 1);

    // ---- phase 2: cand, h_new ----
    f32x4 ac = {};
#pragma unroll
    for (int kk = 0; kk < 8; ++kk) {
      int ku = bKu + kk * 4 + lk;
      int e  = (lr * 128 + ku) * 2;
      u64x2 u;
      u.x = uld64(rh8 + e);
      u.y = uld64(rh8 + e + 1);
      bf16x8 a  = __builtin_bit_cast(bf16x8, u);
      bf16x8 bc = __builtin_bit_cast(bf16x8, Wl[(2 * 16 + lr) * 128 + (ku ^ (lr & 7))]);
      ac = mfma16(a, bc, ac);
    }
#pragma unroll
    for (int q = 0; q < 4; ++q) red[0][wq][lk * 4 + q][lr] = ac[q];
    __syncthreads();
    {
      float sc = red[0][0][b_][cl_] + red[0][1][b_][cl_] + red[0][2][b_][cl_] +
                 red[0][3][b_][cl_] + gc;
      float cand = tanhf(sc);
      float hn = (1.f - zv) * hp + zv * cand;
      hp = hn;
      outh[tb * 1024 + cg] = hn;
      unsigned short my = f2bf(hn);
      allhbf[tb * 1024 + cg] = my;
      unsigned other = __shfl_xor((unsigned)my, 1);
      if ((cl_ & 1) == 0)
        ust32((unsigned*)hbf + ((b_ * 1024 + cg) >> 1), (unsigned)my | (other << 16));
    }
    flag_bar(flags, 2 * t + 2);
  }
}

// ---------------- workspace layout (bytes) ----------------
constexpr size_t OFF_WH  = 0;
constexpr size_t OFF_WX  = OFF_WH + 3ull * 1024 * 1024 * 2;
constexpr size_t OFF_WD  = OFF_WX + 3ull * 1024 * 512 * 2;
constexpr size_t OFF_XE  = OFF_WD + 32000ull * 1024 * 2;
constexpr size_t OFF_GX  = OFF_XE + 4096ull * 512 * 2;
constexpr size_t OFF_AH  = OFF_GX + 4096ull * 3072 * 4;
constexpr size_t OFF_HBF = OFF_AH + 4096ull * 1024 * 2;
constexpr size_t OFF_RH  = OFF_HBF + 16384ull * 2;
constexpr size_t OFF_FLG = OFF_RH + 16384ull * 2;              // 8 KB flags

extern "C" void kernel_launch(void* const* d_in, const int* in_sizes, int n_in,
                              void* d_out, int out_size, void* d_ws, size_t ws_size,
                              hipStream_t stream) {
  const int*   x   = (const int*)d_in[0];
  const float* h0  = (const float*)d_in[1];
  const float* emb = (const float*)d_in[2];
  const float* Wz  = (const float*)d_in[3];
  const float* Wr  = (const float*)d_in[4];
  const float* Wm  = (const float*)d_in[5];
  const float* Wd  = (const float*)d_in[6];

  float* out_h = (float*)d_out;                        // [256*16, 1024]
  float* out_y = out_h + 4096ull * 1024;               // [256*16, 32000]

  char* ws = (char*)d_ws;
  unsigned short* Whall = (unsigned short*)(ws + OFF_WH);
  unsigned short* Wxall = (unsigned short*)(ws + OFF_WX);
  unsigned short* Wdbf  = (unsigned short*)(ws + OFF_WD);
  unsigned short* xebf  = (unsigned short*)(ws + OFF_XE);
  float*          Gx    = (float*)(ws + OFF_GX);
  unsigned short* allh  = (unsigned short*)(ws + OFF_AH);
  unsigned short* hbf   = (unsigned short*)(ws + OFF_HBF);
  unsigned short* rh    = (unsigned short*)(ws + OFF_RH);
  unsigned*       flags = (unsigned*)(ws + OFF_FLG);

  hipMemsetAsync(flags, 0, 8192, stream);

  prep_w <<<4608, 256, 0, stream>>>(Wz, Wr, Wm, Whall, Wxall);
  prep_wd<<<32000, 256, 0, stream>>>(Wd, Wdbf);
  prep_xe<<<2048, 256, 0, stream>>>(x, emb, xebf);
  prep_h <<<64, 256, 0, stream>>>(h0, hbf);

  // Gx[tb][g*1024+c] = xe[tb] . Wx_g[c]   (M=4096, N=3072, K=512)
  gemm_bt<<<dim3(32, 24), 256, 0, stream>>>(xebf, Wxall, Gx,
                                            4096, 3072, 512, 512, 512, 3072);

  gru_persistent<<<NBLK, 256, 0, stream>>>(Whall, Gx, h0, hbf, rh,
                                           out_h, allh, flags);

  // all_y = all_h . Wd^T   (M=4096, N=32000, K=1024)
  gemm_bt<<<dim3(32, 250), 256, 0, stream>>>(allh, Wdbf, out_y,
                                             4096, 32000, 1024, 1024, 1024, 32000);
}

// Round 3
// 1486.465 us; speedup vs baseline: 5.5662x; 1.5298x over previous
//
#include <hip/hip_runtime.h>

// ---------------------------------------------------------------------------
// GRU (T=256, B=16, HID=1024, EMB=512, VOCAB=32000) + vocab projection.
//   prep_*  : cast weights/embeddings to bf16, split W into h-part / x-part
//   gemm_bt : C = A * B^T bf16 MFMA (used for the Gx precompute)
//   mega    : persistent 256-block kernel.
//       blocks 0..63   : GRU recurrence, weights LDS-resident.
//           - cross-block data (h_t, r*h) written UNCACHED (device-scope
//             relaxed atomics -> coherence point), slotted by timestep so
//             every address is write-once -> consumers read CACHED uint4.
//           - grid barrier = per-block flag array, relaxed store + poll.
//           - block 0 publishes gru_step after each step.
//       blocks 64..255 : projection all_y = all_h @ Wd^T pulled from an
//           atomic tile queue, each tile gated on gru_step (rows ready).
//           GRU blocks join the pool after the recurrence finishes.
// ---------------------------------------------------------------------------

using bf16x8 = __attribute__((ext_vector_type(8))) __bf16;
using f32x4  = __attribute__((ext_vector_type(4))) float;

#define GRUB 64
#define TOTB 256
#define NTILE 250          // 32000/128 col tiles
#define NGRP  32           // 4096/128 row groups (8 timesteps each)

__device__ __forceinline__ unsigned short f2bf(float f) {
  unsigned u = __builtin_bit_cast(unsigned, f);
  u += 0x7FFFu + ((u >> 16) & 1u);          // RNE
  return (unsigned short)(u >> 16);
}

__device__ __forceinline__ f32x4 mfma16(bf16x8 a, bf16x8 b, f32x4 c) {
  return __builtin_amdgcn_mfma_f32_16x16x32_bf16(a, b, c, 0, 0, 0);
}

__device__ __forceinline__ void ust32(unsigned* p, unsigned v) {
  __hip_atomic_store(p, v, __ATOMIC_RELAXED, __HIP_MEMORY_SCOPE_AGENT);
}
__device__ __forceinline__ unsigned uld32(const unsigned* p) {
  return __hip_atomic_load(p, __ATOMIC_RELAXED, __HIP_MEMORY_SCOPE_AGENT);
}

// ---------------- prep kernels ----------------

__global__ void prep_w(const float* __restrict__ Wz, const float* __restrict__ Wr,
                       const float* __restrict__ Wm,
                       unsigned short* __restrict__ Whall,
                       unsigned short* __restrict__ Wxall) {
  int i = blockIdx.x * 256 + threadIdx.x;
  int g   = i / 393216;            // 1024*1536/4
  int rem = i % 393216;
  int j   = rem / 384;             // 1536/4
  int k   = (rem % 384) * 4;
  const float* src = (g == 0) ? Wz : (g == 1) ? Wr : Wm;
  float4 v = *(const float4*)(src + (size_t)j * 1536 + k);
  ushort4 o;
  o.x = f2bf(v.x); o.y = f2bf(v.y); o.z = f2bf(v.z); o.w = f2bf(v.w);
  if (k < 1024)
    *(ushort4*)(Whall + ((size_t)(g * 1024 + j) * 1024 + k)) = o;
  else
    *(ushort4*)(Wxall + ((size_t)(g * 1024 + j) * 512 + (k - 1024))) = o;
}

__global__ void prep_wd(const float* __restrict__ Wd, unsigned short* __restrict__ Wdbf) {
  size_t i = (size_t)blockIdx.x * 256 + threadIdx.x;
  float4 v = *(const float4*)(Wd + i * 4);
  ushort4 o;
  o.x = f2bf(v.x); o.y = f2bf(v.y); o.z = f2bf(v.z); o.w = f2bf(v.w);
  *(ushort4*)(Wdbf + i * 4) = o;
}

__global__ void prep_xe(const int* __restrict__ x, const float* __restrict__ emb,
                        unsigned short* __restrict__ xebf) {
  int i  = blockIdx.x * 256 + threadIdx.x;
  int tb = i >> 7, k = (i & 127) * 4;
  int tok = x[tb];
  float4 v = *(const float4*)(emb + (size_t)tok * 512 + k);
  ushort4 o;
  o.x = f2bf(v.x); o.y = f2bf(v.y); o.z = f2bf(v.z); o.w = f2bf(v.w);
  *(ushort4*)(xebf + (size_t)tb * 512 + k) = o;
}

__global__ void prep_h(const float* __restrict__ h, unsigned short* __restrict__ hbf) {
  int i = blockIdx.x * 256 + threadIdx.x;
  hbf[i] = f2bf(h[i]);
}

// ---------------- GEMM: C[M,N] = A[M,K] x B[N,K]^T (Gx precompute) ---------
__global__ __launch_bounds__(256) void gemm_bt(
    const unsigned short* __restrict__ A, const unsigned short* __restrict__ B,
    float* __restrict__ C, int M, int N, int K, int lda, int ldb, int ldc) {
  __shared__ uint4 As[128 * 5];
  __shared__ uint4 Bs[128 * 5];
  const int tid  = threadIdx.x;
  const int wid  = tid >> 6, lane = tid & 63;
  const int wr   = wid >> 1, wc = wid & 1;
  const int m0   = blockIdx.x * 128, n0 = blockIdx.y * 128;
  const int lr   = lane & 15, lk = lane >> 4;

  f32x4 acc[4][4] = {};
  const int nk = K >> 5;
  for (int kt = 0; kt < nk; ++kt) {
#pragma unroll
    for (int c = 0; c < 2; ++c) {
      int chunk = c * 256 + tid;
      int row = chunk >> 2, kc = chunk & 3;
      As[row * 5 + kc] = *(const uint4*)(A + (size_t)(m0 + row) * lda + kt * 32 + kc * 8);
      Bs[row * 5 + kc] = *(const uint4*)(B + (size_t)(n0 + row) * ldb + kt * 32 + kc * 8);
    }
    __syncthreads();
    bf16x8 af[4], bg[4];
#pragma unroll
    for (int i = 0; i < 4; ++i) {
      af[i] = __builtin_bit_cast(bf16x8, As[(wr * 64 + i * 16 + lr) * 5 + lk]);
      bg[i] = __builtin_bit_cast(bf16x8, Bs[(wc * 64 + i * 16 + lr) * 5 + lk]);
    }
#pragma unroll
    for (int i = 0; i < 4; ++i)
#pragma unroll
      for (int j = 0; j < 4; ++j)
        acc[i][j] = mfma16(af[i], bg[j], acc[i][j]);
    __syncthreads();
  }
#pragma unroll
  for (int i = 0; i < 4; ++i) {
    int mb = m0 + wr * 64 + i * 16 + lk * 4;
#pragma unroll
    for (int j = 0; j < 4; ++j) {
      int n = n0 + wc * 64 + j * 16 + lr;
#pragma unroll
      for (int q = 0; q < 4; ++q)
        C[(size_t)(mb + q) * ldc + n] = acc[i][j][q];
    }
  }
}

// ---------------- mega kernel ----------------

// flags layout (uints): [0..2048) barrier flags (bid*32); [2048] gru_step;
// [2080] proj tile counter.
__device__ __forceinline__ void flag_bar(unsigned* flags, unsigned seq) {
  __syncthreads();               // drains vmcnt -> data stores at coherence pt
  if (threadIdx.x < 64) {
    if (threadIdx.x == 0)
      ust32(&flags[blockIdx.x * 32], seq);
    unsigned* f = &flags[threadIdx.x * 32];
    while (uld32(f) < seq) {}
  }
  __syncthreads();
}

__global__ __launch_bounds__(256, 1) void mega(
    const unsigned short* __restrict__ Whall, const float* __restrict__ Gx,
    const unsigned short* __restrict__ h0bf, const float* __restrict__ h0f,
    unsigned short* __restrict__ rhs, float* __restrict__ outh,
    unsigned short* __restrict__ allh,
    const unsigned short* __restrict__ Wdbf, float* __restrict__ outy,
    unsigned* __restrict__ flags) {
  __shared__ uint4 smem[6672];                 // 106752 B, 1 block/CU
  const int tid = threadIdx.x;
  const int bid = blockIdx.x;
  unsigned* stepp = flags + 2048;
  unsigned* ctrp  = flags + 2080;

  if (bid < GRUB) {
    // ------------- GRU recurrence -------------
    uint4* Wl = smem;                                          // 6144 uint4
    float (*red)[4][16][16] = (float (*)[4][16][16])(smem + 6144); // 512 uint4
    const int lane = tid & 63, wq = tid >> 6;
    const int c0   = bid * 16;
    const int lr   = lane & 15, lk = lane >> 4;
    const int bKu  = wq * 32;

    for (int it = 0; it < 24; ++it) {
      int chunk = it * 256 + tid;              // 0..6143
      int g = chunk >> 11, rem = chunk & 2047;
      int cl = rem >> 7, k8 = rem & 127;
      uint4 v = *(const uint4*)(Whall + ((size_t)(g * 1024 + c0 + cl) * 1024 + k8 * 8));
      Wl[(g * 16 + cl) * 128 + (k8 ^ (cl & 7))] = v;
    }

    const int b_  = tid >> 4, cl_ = tid & 15;
    const int cg  = c0 + cl_;
    float hp = h0f[b_ * 1024 + cg];            // h lives in registers
    float zv = 0.f;
    __syncthreads();

    for (int t = 0; t < 256; ++t) {
      const size_t tb = (size_t)t * 16 + b_;
      float gz = Gx[tb * 3072 + cg];
      float gr = Gx[tb * 3072 + 1024 + cg];
      float gc = Gx[tb * 3072 + 2048 + cg];

      // ---- phase 1: z, r (h_prev read CACHED from write-once slot) ----
      const uint4* hp4 = (t == 0) ? (const uint4*)h0bf
                                  : (const uint4*)(allh + (size_t)(t - 1) * 16384);
      f32x4 az = {}, ar = {};
#pragma unroll
      for (int kk = 0; kk < 8; ++kk) {
        int ku = bKu + kk * 4 + lk;            // 0..127
        bf16x8 a  = __builtin_bit_cast(bf16x8, hp4[lr * 128 + ku]);
        bf16x8 bz = __builtin_bit_cast(bf16x8, Wl[(0 * 16 + lr) * 128 + (ku ^ (lr & 7))]);
        bf16x8 br = __builtin_bit_cast(bf16x8, Wl[(1 * 16 + lr) * 128 + (ku ^ (lr & 7))]);
        az = mfma16(a, bz, az);
        ar = mfma16(a, br, ar);
      }
#pragma unroll
      for (int q = 0; q < 4; ++q) {
        red[0][wq][lk * 4 + q][lr] = az[q];
        red[1][wq][lk * 4 + q][lr] = ar[q];
      }
      __syncthreads();
      {
        float sz = red[0][0][b_][cl_] + red[0][1][b_][cl_] + red[0][2][b_][cl_] +
                   red[0][3][b_][cl_] + gz;
        float sr = red[1][0][b_][cl_] + red[1][1][b_][cl_] + red[1][2][b_][cl_] +
                   red[1][3][b_][cl_] + gr;
        zv = 1.f / (1.f + __expf(-sz));
        float rv = 1.f / (1.f + __expf(-sr));
        unsigned short my = f2bf(rv * hp);
        unsigned other = __shfl_xor((unsigned)my, 1);
        if ((cl_ & 1) == 0)
          ust32((unsigned*)rhs + (((size_t)t * 16384 + b_ * 1024 + cg) >> 1),
                (unsigned)my | (other << 16));
      }
      flag_bar(flags, 2 * t + 1);

      // ---- phase 2: cand, h_new (rh read CACHED from write-once slot) ----
      const uint4* rt4 = (const uint4*)(rhs + (size_t)t * 16384);
      f32x4 ac = {};
#pragma unroll
      for (int kk = 0; kk < 8; ++kk) {
        int ku = bKu + kk * 4 + lk;
        bf16x8 a  = __builtin_bit_cast(bf16x8, rt4[lr * 128 + ku]);
        bf16x8 bc = __builtin_bit_cast(bf16x8, Wl[(2 * 16 + lr) * 128 + (ku ^ (lr & 7))]);
        ac = mfma16(a, bc, ac);
      }
#pragma unroll
      for (int q = 0; q < 4; ++q) red[0][wq][lk * 4 + q][lr] = ac[q];
      __syncthreads();
      {
        float sc = red[0][0][b_][cl_] + red[0][1][b_][cl_] + red[0][2][b_][cl_] +
                   red[0][3][b_][cl_] + gc;
        float cand = tanhf(sc);
        float hn = (1.f - zv) * hp + zv * cand;
        hp = hn;
        outh[tb * 1024 + cg] = hn;
        unsigned short my = f2bf(hn);
        unsigned other = __shfl_xor((unsigned)my, 1);
        if ((cl_ & 1) == 0)
          ust32((unsigned*)allh + (((size_t)t * 16384 + b_ * 1024 + cg) >> 1),
                (unsigned)my | (other << 16));
      }
      flag_bar(flags, 2 * t + 2);
      if (bid == 0 && tid == 0) ust32(stepp, t + 1);
    }
  }

  // ------------- projection tile pool -------------
  // blocks 64..255 arrive immediately; GRU blocks join after the recurrence.
  __syncthreads();
  uint4* As = smem;
  uint4* Bs = smem + 640;
  unsigned* wsh = (unsigned*)(smem + 6656);
  const int wid = tid >> 6, lane = tid & 63;
  const int wr = wid >> 1, wc = wid & 1;
  const int lr = lane & 15, lk = lane >> 4;

  for (;;) {
    __syncthreads();
    if (tid == 0) {
      unsigned w = __hip_atomic_fetch_add(ctrp, 1u, __ATOMIC_RELAXED,
                                          __HIP_MEMORY_SCOPE_AGENT);
      if (w < (unsigned)(NGRP * NTILE)) {
        unsigned need = (w / NTILE) * 8u + 8u;         // steps done for group
        while (uld32(stepp) < need) __builtin_amdgcn_s_sleep(32);
      }
      *wsh = w;
    }
    __syncthreads();
    unsigned w = *wsh;
    if (w >= (unsigned)(NGRP * NTILE)) break;
    int g = w / NTILE, nt = w % NTILE;
    int m0 = g * 128, n0 = nt * 128;

    f32x4 acc[4][4] = {};
    for (int kt = 0; kt < 32; ++kt) {
#pragma unroll
      for (int c = 0; c < 2; ++c) {
        int chunk = c * 256 + tid;
        int row = chunk >> 2, kc = chunk & 3;
        As[row * 5 + kc] = *(const uint4*)(allh + (size_t)(m0 + row) * 1024 + kt * 32 + kc * 8);
        Bs[row * 5 + kc] = *(const uint4*)(Wdbf + (size_t)(n0 + row) * 1024 + kt * 32 + kc * 8);
      }
      __syncthreads();
      bf16x8 af[4], bg[4];
#pragma unroll
      for (int i = 0; i < 4; ++i) {
        af[i] = __builtin_bit_cast(bf16x8, As[(wr * 64 + i * 16 + lr) * 5 + lk]);
        bg[i] = __builtin_bit_cast(bf16x8, Bs[(wc * 64 + i * 16 + lr) * 5 + lk]);
      }
#pragma unroll
      for (int i = 0; i < 4; ++i)
#pragma unroll
        for (int j = 0; j < 4; ++j)
          acc[i][j] = mfma16(af[i], bg[j], acc[i][j]);
      __syncthreads();
    }
#pragma unroll
    for (int i = 0; i < 4; ++i) {
      int mb = m0 + wr * 64 + i * 16 + lk * 4;
#pragma unroll
      for (int j = 0; j < 4; ++j) {
        int n = n0 + wc * 64 + j * 16 + lr;
#pragma unroll
        for (int q = 0; q < 4; ++q)
          outy[(size_t)(mb + q) * 32000 + n] = acc[i][j][q];
      }
    }
  }
}

// ---------------- workspace layout (bytes) ----------------
constexpr size_t OFF_WH  = 0;                                  // 6 MB
constexpr size_t OFF_WX  = OFF_WH + 3ull * 1024 * 1024 * 2;    // 3 MB
constexpr size_t OFF_WD  = OFF_WX + 3ull * 1024 * 512 * 2;     // 65.5 MB
constexpr size_t OFF_XE  = OFF_WD + 32000ull * 1024 * 2;       // 4.2 MB
constexpr size_t OFF_GX  = OFF_XE + 4096ull * 512 * 2;         // 50.3 MB
constexpr size_t OFF_AH  = OFF_GX + 4096ull * 3072 * 4;        // 8.4 MB
constexpr size_t OFF_H0  = OFF_AH + 4096ull * 1024 * 2;        // 32 KB
constexpr size_t OFF_RHS = OFF_H0 + 16384ull * 2;              // 8.4 MB
constexpr size_t OFF_FLG = OFF_RHS + 256ull * 16384 * 2;       // 16 KB

extern "C" void kernel_launch(void* const* d_in, const int* in_sizes, int n_in,
                              void* d_out, int out_size, void* d_ws, size_t ws_size,
                              hipStream_t stream) {
  const int*   x   = (const int*)d_in[0];
  const float* h0  = (const float*)d_in[1];
  const float* emb = (const float*)d_in[2];
  const float* Wz  = (const float*)d_in[3];
  const float* Wr  = (const float*)d_in[4];
  const float* Wm  = (const float*)d_in[5];
  const float* Wd  = (const float*)d_in[6];

  float* out_h = (float*)d_out;                        // [256*16, 1024]
  float* out_y = out_h + 4096ull * 1024;               // [256*16, 32000]

  char* ws = (char*)d_ws;
  unsigned short* Whall = (unsigned short*)(ws + OFF_WH);
  unsigned short* Wxall = (unsigned short*)(ws + OFF_WX);
  unsigned short* Wdbf  = (unsigned short*)(ws + OFF_WD);
  unsigned short* xebf  = (unsigned short*)(ws + OFF_XE);
  float*          Gx    = (float*)(ws + OFF_GX);
  unsigned short* allh  = (unsigned short*)(ws + OFF_AH);
  unsigned short* h0bf  = (unsigned short*)(ws + OFF_H0);
  unsigned short* rhs   = (unsigned short*)(ws + OFF_RHS);
  unsigned*       flags = (unsigned*)(ws + OFF_FLG);

  hipMemsetAsync(flags, 0, 16384, stream);

  prep_w <<<4608, 256, 0, stream>>>(Wz, Wr, Wm, Whall, Wxall);
  prep_wd<<<32000, 256, 0, stream>>>(Wd, Wdbf);
  prep_xe<<<2048, 256, 0, stream>>>(x, emb, xebf);
  prep_h <<<64, 256, 0, stream>>>(h0, h0bf);

  // Gx[tb][g*1024+c] = xe[tb] . Wx_g[c]   (M=4096, N=3072, K=512)
  gemm_bt<<<dim3(32, 24), 256, 0, stream>>>(xebf, Wxall, Gx,
                                            4096, 3072, 512, 512, 512, 3072);

  mega<<<TOTB, 256, 0, stream>>>(Whall, Gx, h0bf, h0, rhs,
                                 out_h, allh, Wdbf, out_y, flags);
}